// Round 6
// baseline (1500.604 us; speedup 1.0000x reference)
//
#include <hip/hip_runtime.h>
#include <hip/hip_bf16.h>

#define NND 100000
#define NED 3200000
#define F 256
#define NCLS 64
#define GSZ 49              // dst nodes per group (one wave per group)
#define NGRP 2048           // groups; ceil(100000/49)=2041 used
#define NBKT 64             // src buckets: b = src>>11 in [0,49)
#define NHIST (NGRP * NBKT) // 131072 = 512*256 exactly

typedef _Float16 f16x8 __attribute__((ext_vector_type(8)));
typedef _Float16 f16x4 __attribute__((ext_vector_type(4)));
typedef _Float16 f16x2 __attribute__((ext_vector_type(2)));
typedef float f32x4 __attribute__((ext_vector_type(4)));

// ---------------- fused degree + (group,bucket) histogram ----------------
__global__ __launch_bounds__(256) void k_hist(const int* __restrict__ src, const int* __restrict__ dst,
                                              int* __restrict__ deg, int* __restrict__ gbh) {
    int i = blockIdx.x * 256 + threadIdx.x;
    if (i < NED) {
        int d = dst[i];
        int s = src[i];
        atomicAdd(&deg[d], 1);
        atomicAdd(&gbh[(d / GSZ) * NBKT + (s >> 11)], 1);
    }
}

// ---------------- scan of NHIST (block-local pass) ----------------
__global__ __launch_bounds__(256) void k_scan1(int* data, int* bsum, int n) {
    __shared__ int sh[256];
    int i = blockIdx.x * 256 + threadIdx.x;
    int v = (i < n) ? data[i] : 0;
    sh[threadIdx.x] = v;
    __syncthreads();
    for (int off = 1; off < 256; off <<= 1) {
        int t = (threadIdx.x >= off) ? sh[threadIdx.x - off] : 0;
        __syncthreads();
        sh[threadIdx.x] += t;
        __syncthreads();
    }
    if (i < n) data[i] = sh[threadIdx.x] - v;  // exclusive within block
    if (threadIdx.x == 255) bsum[blockIdx.x] = sh[255];
}

__global__ __launch_bounds__(512) void k_scan2(int* __restrict__ bsum, int nb) {
    __shared__ int sh[512];
    int tid = threadIdx.x;
    int v = (tid < nb) ? bsum[tid] : 0;
    sh[tid] = v;
    __syncthreads();
    for (int off = 1; off < 512; off <<= 1) {
        int t = (tid >= off) ? sh[tid - off] : 0;
        __syncthreads();
        sh[tid] += t;
        __syncthreads();
    }
    if (tid < nb) bsum[tid] = sh[tid] - v;  // exclusive
}

// add-back + cursor copy + per-node norm (NND < NHIST so fold norm here)
__global__ __launch_bounds__(256) void k_scan3(int* __restrict__ start, int* __restrict__ cursor,
                                               const int* __restrict__ bsum, const int* __restrict__ deg,
                                               float* __restrict__ norm, int n) {
    int i = blockIdx.x * 256 + threadIdx.x;
    if (i < n) {
        int v = start[i] + bsum[blockIdx.x];
        start[i] = v;
        cursor[i] = v;
        if (i < NND) {
            float d = (float)deg[i];
            norm[i] = rsqrtf(d < 1.0f ? 1.0f : d);
        }
    }
}

// ---------------- fill: scatter edges into (group, src-bucket) segments ----------------
__global__ __launch_bounds__(256) void k_fill2(const int* __restrict__ src, const int* __restrict__ dst,
                                               int* __restrict__ cur, int* __restrict__ col2) {
    int i = blockIdx.x * 256 + threadIdx.x;
    if (i < NED) {
        int s = src[i], d = dst[i];
        int g = d / GSZ;
        int p = atomicAdd(&cur[g * NBKT + (s >> 11)], 1);
        col2[p] = (s << 6) | (d - g * GSZ);
    }
}

// ---------------- LayerNorm (one wave per node) -> pre-scaled fp16 (norm * LN) ----------------
__global__ __launch_bounds__(256) void k_ln(const float* __restrict__ x, const float* __restrict__ gamma,
                                            const float* __restrict__ beta, const float* __restrict__ norm,
                                            _Float16* __restrict__ y) {
    int node = blockIdx.x * 4 + (threadIdx.x >> 6);
    int lane = threadIdx.x & 63;
    if (node >= NND) return;
    float4 v = ((const float4*)x)[node * 64 + lane];
    float s = v.x + v.y + v.z + v.w;
    float s2 = v.x * v.x + v.y * v.y + v.z * v.z + v.w * v.w;
    for (int m = 1; m < 64; m <<= 1) {
        s += __shfl_xor(s, m, 64);
        s2 += __shfl_xor(s2, m, 64);
    }
    float mu = s * (1.0f / 256.0f);
    float var = s2 * (1.0f / 256.0f) - mu * mu;
    float rs = rsqrtf(var + 1e-5f);
    float w = norm[node];
    float4 g = ((const float4*)gamma)[lane];
    float4 b = ((const float4*)beta)[lane];
    f16x4 o;
    o[0] = (_Float16)(w * ((v.x - mu) * rs * g.x + b.x));
    o[1] = (_Float16)(w * ((v.y - mu) * rs * g.y + b.y));
    o[2] = (_Float16)(w * ((v.z - mu) * rs * g.z + b.z));
    o[3] = (_Float16)(w * ((v.w - mu) * rs * g.w + b.w));
    *(f16x4*)(y + (size_t)node * F + lane * 4) = o;
}

// ---------------- aligned-sweep hop: one wave per group, LDS fp16 accumulators ----------------
// Processes feature half P (runtime 0/1). x pre-scaled by norm.
// LAST=0: write norm^2 * sum. LAST=1: write norm * sum.
template <int LAST>
__global__ __launch_bounds__(64) void k_hop(const _Float16* __restrict__ x, _Float16* __restrict__ y,
                                            const int* __restrict__ gbs, const int* __restrict__ col2,
                                            const float* __restrict__ norm, int P) {
    int g = blockIdx.x;
    int n0 = g * GSZ;
    if (n0 >= NND) return;
    int lane = threadIdx.x;
    __shared__ unsigned int accu[GSZ * 64];   // 49 nodes x 128 feats (f16x2 per lane) = 12544 B
#pragma unroll
    for (int i = 0; i < GSZ; i++) accu[i * 64 + lane] = 0;

    int e0 = gbs[g * NBKT];
    int e1 = (g == NGRP - 1) ? NED : gbs[(g + 1) * NBKT];
    const _Float16* xb = x + P * 128;

    int e = e0;
    for (; e + 8 <= e1; e += 8) {
        int vv[8];
        f16x2 av[8];
#pragma unroll
        for (int k = 0; k < 8; k++) vv[k] = col2[e + k];
#pragma unroll
        for (int k = 0; k < 8; k++)
            av[k] = *(const f16x2*)(xb + (size_t)(vv[k] >> 6) * F + lane * 2);
#pragma unroll
        for (int k = 0; k < 8; k++) {
            f16x2* p = (f16x2*)&accu[(vv[k] & 63) * 64 + lane];
            *p = *p + av[k];
        }
    }
    for (; e < e1; e++) {
        int v = col2[e];
        f16x2 a = *(const f16x2*)(xb + (size_t)(v >> 6) * F + lane * 2);
        f16x2* p = (f16x2*)&accu[(v & 63) * 64 + lane];
        *p = *p + a;
    }

    int nn = NND - n0;
    if (nn > GSZ) nn = GSZ;
    for (int dl = 0; dl < nn; dl++) {
        int node = n0 + dl;
        float wd = norm[node];
        float sc = LAST ? wd : wd * wd;
        f16x2 a = *(f16x2*)&accu[dl * 64 + lane];
        f16x2 o;
        o[0] = (_Float16)((float)a[0] * sc);
        o[1] = (_Float16)((float)a[1] * sc);
        *(f16x2*)(y + (size_t)node * F + P * 128 + lane * 2) = o;
    }
}

// ---------------- fp32 -> fp16 cast of both weight matrices (one launch) ----------------
__global__ __launch_bounds__(256) void k_castW(const float4* __restrict__ Wc, const float4* __restrict__ Wf,
                                               f16x4* __restrict__ WcO, f16x4* __restrict__ WfO) {
    int i = blockIdx.x * 256 + threadIdx.x;
    if (i < F * F / 4) {
        float4 v = Wc[i];
        f16x4 o;
        o[0] = (_Float16)v.x; o[1] = (_Float16)v.y; o[2] = (_Float16)v.z; o[3] = (_Float16)v.w;
        WcO[i] = o;
    } else {
        int j = i - F * F / 4;
        if (j < NCLS * F / 4) {
            float4 v = Wf[j];
            f16x4 o;
            o[0] = (_Float16)v.x; o[1] = (_Float16)v.y; o[2] = (_Float16)v.z; o[3] = (_Float16)v.w;
            WfO[j] = o;
        }
    }
}

// ---------------- fused GEMM: relu(h3 @ Wc^T + bc) @ Wf^T + bf ----------------
__global__ __launch_bounds__(256) void k_gemm(const _Float16* __restrict__ A,
                                              const _Float16* __restrict__ Wc, const float* __restrict__ bc,
                                              const _Float16* __restrict__ Wf, const float* __restrict__ bf,
                                              float* __restrict__ out) {
    __shared__ _Float16 mid[16][264];   // +8 pad kills bank conflicts
    int wave = threadIdx.x >> 6, lane = threadIdx.x & 63;
    int l15 = lane & 15, lhi = lane >> 4;
    int row0 = blockIdx.x * 16;
    const _Float16* arow = A + (size_t)(row0 + l15) * F + lhi * 8;
    int ncol0 = wave * 64;
    f32x4 acc[4];
    for (int t = 0; t < 4; t++) acc[t] = (f32x4){0.f, 0.f, 0.f, 0.f};
#pragma unroll
    for (int kt = 0; kt < 8; kt++) {
        f16x8 a = *(const f16x8*)(arow + kt * 32);
#pragma unroll
        for (int t = 0; t < 4; t++) {
            int n = ncol0 + t * 16 + l15;
            f16x8 b = *(const f16x8*)(Wc + (size_t)n * F + lhi * 8 + kt * 32);
            acc[t] = __builtin_amdgcn_mfma_f32_16x16x32_f16(a, b, acc[t], 0, 0, 0);
        }
    }
#pragma unroll
    for (int t = 0; t < 4; t++) {
        int colb = ncol0 + t * 16 + l15;
        float bv = bc[colb];
#pragma unroll
        for (int r = 0; r < 4; r++) {
            float v = acc[t][r] + bv;
            mid[lhi * 4 + r][colb] = (_Float16)(v > 0.f ? v : 0.f);
        }
    }
    __syncthreads();
    f32x4 acc2 = (f32x4){0.f, 0.f, 0.f, 0.f};
    int colb = wave * 16 + l15;
    const _Float16* brow = Wf + (size_t)colb * F + lhi * 8;
#pragma unroll
    for (int kt = 0; kt < 8; kt++) {
        f16x8 a = *(const f16x8*)&mid[l15][lhi * 8 + kt * 32];
        f16x8 b = *(const f16x8*)(brow + kt * 32);
        acc2 = __builtin_amdgcn_mfma_f32_16x16x32_f16(a, b, acc2, 0, 0, 0);
    }
    float bv = bf[colb];
#pragma unroll
    for (int r = 0; r < 4; r++) {
        int row = row0 + lhi * 4 + r;
        out[(size_t)row * NCLS + colb] = acc2[r] + bv;
    }
}

extern "C" void kernel_launch(void* const* d_in, const int* in_sizes, int n_in,
                              void* d_out, int out_size, void* d_ws, size_t ws_size,
                              hipStream_t stream) {
    const float* features = (const float*)d_in[0];
    const int* edge_src = (const int*)d_in[1];
    const int* edge_dst = (const int*)d_in[2];
    const float* ln_gamma = (const float*)d_in[3];
    const float* ln_beta = (const float*)d_in[4];
    const float* W_conv = (const float*)d_in[5];
    const float* b_conv = (const float*)d_in[6];
    const float* W_fc = (const float*)d_in[7];
    const float* b_fc = (const float*)d_in[8];
    float* out = (float*)d_out;

    char* w = (char*)d_ws;
    const size_t HB2 = (size_t)NND * F * 2;            // 51,200,000 (fp16 h)
    _Float16* hA = (_Float16*)(w + 0);
    _Float16* hB = (_Float16*)(w + HB2);
    int* col2 = (int*)(w + 2 * HB2);                   // 102,400,000 (12.8 MB)
    int* deg = (int*)(w + 115200000);                  // 400,000
    int* gbh = (int*)(w + 115600000);                  // 524,288 (hist -> scanned offsets)
    float* norm = (float*)(w + 116124288);             // 400,000
    int* gbc = (int*)(w + 116524288);                  // 524,288 (cursor)
    int* bsum = (int*)(w + 117048576);                 // 2,048
    _Float16* Wc16 = (_Float16*)(w + 117050624);
    _Float16* Wf16 = (_Float16*)(w + 117181696);

    hipMemsetAsync(deg, 0, 924288, stream);            // deg + gbh in one shot

    const int EB = (NED + 255) / 256;   // 12500

    k_hist<<<EB, 256, 0, stream>>>(edge_src, edge_dst, deg, gbh);
    k_scan1<<<NHIST / 256, 256, 0, stream>>>(gbh, bsum, NHIST);
    k_scan2<<<1, 512, 0, stream>>>(bsum, NHIST / 256);
    k_scan3<<<NHIST / 256, 256, 0, stream>>>(gbh, gbc, bsum, deg, norm, NHIST);
    k_fill2<<<EB, 256, 0, stream>>>(edge_src, edge_dst, gbc, col2);

    k_ln<<<NND / 4, 256, 0, stream>>>(features, ln_gamma, ln_beta, norm, hA);

    k_hop<0><<<NGRP, 64, 0, stream>>>(hA, hB, gbh, col2, norm, 0);
    k_hop<0><<<NGRP, 64, 0, stream>>>(hA, hB, gbh, col2, norm, 1);
    k_hop<0><<<NGRP, 64, 0, stream>>>(hB, hA, gbh, col2, norm, 0);
    k_hop<0><<<NGRP, 64, 0, stream>>>(hB, hA, gbh, col2, norm, 1);
    k_hop<1><<<NGRP, 64, 0, stream>>>(hA, hB, gbh, col2, norm, 0);
    k_hop<1><<<NGRP, 64, 0, stream>>>(hA, hB, gbh, col2, norm, 1);

    k_castW<<<(F * F / 4 + NCLS * F / 4 + 255) / 256, 256, 0, stream>>>(
        (const float4*)W_conv, (const float4*)W_fc, (f16x4*)Wc16, (f16x4*)Wf16);

    k_gemm<<<NND / 16, 256, 0, stream>>>(hB, Wc16, b_conv, Wf16, b_fc, out);
}